// Round 1
// baseline (337.705 us; speedup 1.0000x reference)
//
#include <hip/hip_runtime.h>

typedef unsigned short u16;
typedef __attribute__((ext_vector_type(8))) short bf16x8;
typedef __attribute__((ext_vector_type(16))) float floatx16;

#define C2 0.18033688011112042f  // log2(e)/8 : folds the 1/sqrt(64) score scale into exp2

static __device__ __forceinline__ u16 f2b(float f) {
  unsigned u = __builtin_bit_cast(unsigned, f);
  u = (u + 0x7FFFu + ((u >> 16) & 1u)) >> 16;  // RNE fp32->bf16 (no NaN inputs here)
  return (u16)u;
}
static __device__ __forceinline__ unsigned pk2(float a, float b) {
  return (unsigned)f2b(a) | ((unsigned)f2b(b) << 16);
}
static __device__ __forceinline__ void gl_lds16(const void* g, void* l) {
  __builtin_amdgcn_global_load_lds(
      (const __attribute__((address_space(1))) unsigned*)g,
      (__attribute__((address_space(3))) unsigned*)l, 16, 0, 0);
}

// ---------------- convert X: f32 -> bf16, flat ----------------
__global__ __launch_bounds__(256) void convx_k(
    const float* __restrict__ x0, const float* __restrict__ x1, const float* __restrict__ x2,
    u16* __restrict__ o0, u16* __restrict__ o1, u16* __restrict__ o2) {
  int z = blockIdx.z;
  const float* x = z == 0 ? x0 : (z == 1 ? x1 : x2);
  u16* o = z == 0 ? o0 : (z == 1 ? o1 : o2);
  size_t i = ((size_t)blockIdx.x * 256 + threadIdx.x) * 8;
  float4 a = *(const float4*)(x + i);
  float4 b = *(const float4*)(x + i + 4);
  uint4 u;
  u.x = pk2(a.x, a.y); u.y = pk2(a.z, a.w);
  u.z = pk2(b.x, b.y); u.w = pk2(b.z, b.w);
  *(uint4*)(o + i) = u;
}

// ------- convert+transpose W: [H][1024][64] f32 -> Wt[(h*64+col)][1024] bf16 -------
__global__ __launch_bounds__(256) void convw_k(
    const float* __restrict__ w0, const float* __restrict__ w1, const float* __restrict__ w2,
    u16* __restrict__ o0, u16* __restrict__ o1, u16* __restrict__ o2) {
  int z = blockIdx.z;
  const float* W = z == 0 ? w0 : (z == 1 ? w1 : w2);
  u16* O = z == 0 ? o0 : (z == 1 ? o1 : o2);
  int h = blockIdx.x >> 4, d0 = (blockIdx.x & 15) * 64;
  __shared__ __align__(16) float tile[64 * 68];
  int t = threadIdx.x;
  {
    int r = t >> 2, c = t & 3;
    const float* src = W + (size_t)h * 65536 + (size_t)(d0 + r) * 64 + c * 16;
#pragma unroll
    for (int i = 0; i < 4; ++i) {
      float4 v = *(const float4*)(src + 4 * i);
      *(float4*)&tile[r * 68 + c * 16 + 4 * i] = v;
    }
  }
  __syncthreads();
  {
    int k = t >> 2, dc = t & 3;
    unsigned u[8];
#pragma unroll
    for (int i = 0; i < 8; ++i) {
      float a = tile[(dc * 16 + 2 * i) * 68 + k];
      float b = tile[(dc * 16 + 2 * i + 1) * 68 + k];
      u[i] = pk2(a, b);
    }
    u16* dst = O + ((size_t)(h * 64 + k)) * 1024 + d0 + dc * 16;
    *(uint4*)dst = make_uint4(u[0], u[1], u[2], u[3]);
    *(uint4*)(dst + 8) = make_uint4(u[4], u[5], u[6], u[7]);
  }
}

// ---------------- projection GEMM: C[n][col] = X[n][:] . Wt[col][:] + b[col] ----------------
// out layout head-major: out[h][n][cl] bf16.  128x128 tile, BK=32, 4 waves (2x2), 32x32x16 MFMA.
__global__ __launch_bounds__(256, 3) void proj_k(
    const u16* __restrict__ x0, const u16* __restrict__ x1, const u16* __restrict__ x2,
    const u16* __restrict__ w0, const u16* __restrict__ w1, const u16* __restrict__ w2,
    const float* __restrict__ b0, const float* __restrict__ b1, const float* __restrict__ b2,
    u16* __restrict__ q0, u16* __restrict__ q1, u16* __restrict__ q2) {
  int z = blockIdx.z;
  const u16* X = z == 0 ? x0 : (z == 1 ? x1 : x2);
  const u16* Wt = z == 0 ? w0 : (z == 1 ? w1 : w2);
  const float* bias = z == 0 ? b0 : (z == 1 ? b1 : b2);
  u16* out = z == 0 ? q0 : (z == 1 ? q1 : q2);

  __shared__ uint4 smem4[16384 / 16];
  char* sm = (char*)smem4;  // A tile [128][32] @0 (64B rows), B tile @8192
  const int t = threadIdx.x, lane = t & 63, wid = t >> 6;
  const int L = lane & 31, h2 = lane >> 5;
  const int wm = wid >> 1, wc = wid & 1;
  const int n0 = blockIdx.y * 128, c0 = blockIdx.x * 128;

  floatx16 acc[2][2];
#pragma unroll
  for (int a = 0; a < 2; ++a)
#pragma unroll
    for (int b = 0; b < 2; ++b)
#pragma unroll
      for (int r = 0; r < 16; ++r) acc[a][b][r] = 0.f;

  const int srow = t >> 2, sc = t & 3;
  for (int k0 = 0; k0 < 1024; k0 += 32) {
#pragma unroll
    for (int i = 0; i < 2; ++i) {
      int row = i * 64 + srow;
      int cg = sc ^ ((row >> 1) & 3);  // XOR swizzle 16B chunks within 64B rows
      gl_lds16(X + (size_t)(n0 + row) * 1024 + k0 + cg * 8, sm + i * 4096 + wid * 1024);
    }
#pragma unroll
    for (int i = 0; i < 2; ++i) {
      int row = i * 64 + srow;
      int cg = sc ^ ((row >> 1) & 3);
      gl_lds16(Wt + (size_t)(c0 + row) * 1024 + k0 + cg * 8, sm + 8192 + i * 4096 + wid * 1024);
    }
    __syncthreads();
#pragma unroll
    for (int ks = 0; ks < 2; ++ks) {
      bf16x8 af[2], bfr[2];
#pragma unroll
      for (int mt = 0; mt < 2; ++mt) {
        int m = wm * 64 + mt * 32 + L;
        int cc = (2 * ks + h2) ^ ((m >> 1) & 3);
        af[mt] = *(const bf16x8*)(sm + m * 64 + cc * 16);
      }
#pragma unroll
      for (int ct = 0; ct < 2; ++ct) {
        int c = wc * 64 + ct * 32 + L;
        int cc = (2 * ks + h2) ^ ((c >> 1) & 3);
        bfr[ct] = *(const bf16x8*)(sm + 8192 + c * 64 + cc * 16);
      }
#pragma unroll
      for (int mt = 0; mt < 2; ++mt)
#pragma unroll
        for (int ct = 0; ct < 2; ++ct)
          acc[mt][ct] = __builtin_amdgcn_mfma_f32_32x32x16_bf16(af[mt], bfr[ct], acc[mt][ct], 0, 0, 0);
    }
    __syncthreads();
  }
#pragma unroll
  for (int ct = 0; ct < 2; ++ct) {
    int gcol = c0 + wc * 64 + ct * 32 + L;
    float bv = bias[gcol];
    int h = gcol >> 6, cl = gcol & 63;
#pragma unroll
    for (int mt = 0; mt < 2; ++mt)
#pragma unroll
      for (int r = 0; r < 16; ++r) {
        int seq = n0 + wm * 64 + mt * 32 + (r & 3) + 8 * (r >> 2) + 4 * h2;
        out[((size_t)h * 4096 + seq) * 64 + cl] = f2b(acc[mt][ct][r] + bv);
      }
  }
}

// ---------------- V transpose: V[h][n][v] -> VT[h][v][n] (bf16) ----------------
__global__ __launch_bounds__(256) void vtrans_k(const u16* __restrict__ V, u16* __restrict__ VT) {
  int h = blockIdx.x & 15, nb = blockIdx.x >> 4;
  __shared__ __align__(16) u16 tile[64 * 72];
  int t = threadIdx.x;
  {
    int r = t >> 2, c = t & 3;
    const u16* src = V + ((size_t)(h * 4096 + nb * 64 + r)) * 64 + c * 16;
    *(bf16x8*)&tile[r * 72 + c * 16] = *(const bf16x8*)src;
    *(bf16x8*)&tile[r * 72 + c * 16 + 8] = *(const bf16x8*)(src + 8);
  }
  __syncthreads();
  {
    int v = t >> 2, nc = t & 3;
    unsigned u[8];
#pragma unroll
    for (int i = 0; i < 8; ++i) {
      unsigned lo = tile[(nc * 16 + 2 * i) * 72 + v];
      unsigned hi = tile[(nc * 16 + 2 * i + 1) * 72 + v];
      u[i] = lo | (hi << 16);
    }
    u16* dst = VT + ((size_t)(h * 64 + v)) * 4096 + nb * 64 + nc * 16;
    *(uint4*)dst = make_uint4(u[0], u[1], u[2], u[3]);
    *(uint4*)(dst + 8) = make_uint4(u[4], u[5], u[6], u[7]);
  }
}

// ---------------- flash attention, split-K=2, S^T orientation ----------------
// block = 128 thr (2 waves); wave owns 64 queries; BN=64 keys/iter; 32 iters over 2048 keys.
// S^T[m][n] = K.Q^T (A=K frags, B=Q regs); softmax stats per col n = lane&31 (shfl_xor 32);
// P^T round-trips wave-private LDS (b64 packed writes); O^T = V^T . P^T.
__global__ __launch_bounds__(128, 2) void attn_k(
    const u16* __restrict__ Q, const u16* __restrict__ K, const u16* __restrict__ VT,
    float* __restrict__ Op, float* __restrict__ Mst, float* __restrict__ Lst) {
  __shared__ uint4 smem4[34816 / 16];
  char* sm = (char*)smem4;  // K tile 8KB @0, VT tile 8KB @8192, P 2x9216 @16384
  const int t = threadIdx.x, lane = t & 63, wid = t >> 6;
  const int L = lane & 31, h2 = lane >> 5;
  const int bid = blockIdx.x;
  const int h = bid & 15, st = (bid >> 4) & 31, sp = bid >> 9;  // h in low bits -> XCD locality
  const int n0 = st * 128 + wid * 64;
  char* Pb = sm + 16384 + wid * 9216;  // P^T[n][m], stride 144B (128B + 16B pad)

  bf16x8 qf[2][4];
#pragma unroll
  for (int nt = 0; nt < 2; ++nt)
#pragma unroll
    for (int ks = 0; ks < 4; ++ks)
      qf[nt][ks] = *(const bf16x8*)(Q + ((size_t)(h * 4096 + n0 + nt * 32 + L)) * 64 + ks * 16 + h2 * 8);

  floatx16 accO[2][2];
#pragma unroll
  for (int a = 0; a < 2; ++a)
#pragma unroll
    for (int b = 0; b < 2; ++b)
#pragma unroll
      for (int r = 0; r < 16; ++r) accO[a][b][r] = 0.f;
  float m_run[2] = {-__builtin_inff(), -__builtin_inff()};
  float l_run[2] = {0.f, 0.f};

  const int srow = t >> 3, sc = t & 7;
  for (int it = 0; it < 32; ++it) {
    const int m0 = sp * 2048 + it * 64;
#pragma unroll
    for (int i = 0; i < 4; ++i) {
      int row = i * 16 + srow;
      int cg = sc ^ (row & 7);
      gl_lds16(K + ((size_t)(h * 4096 + m0 + row)) * 64 + cg * 8, sm + i * 2048 + wid * 1024);
    }
#pragma unroll
    for (int i = 0; i < 4; ++i) {
      int vr = i * 16 + srow;
      int cg = sc ^ (vr & 7);
      gl_lds16(VT + ((size_t)(h * 64 + vr)) * 4096 + m0 + cg * 8, sm + 8192 + i * 2048 + wid * 1024);
    }
    __syncthreads();

    floatx16 accS[2][2];
#pragma unroll
    for (int a = 0; a < 2; ++a)
#pragma unroll
      for (int b = 0; b < 2; ++b)
#pragma unroll
        for (int r = 0; r < 16; ++r) accS[a][b][r] = 0.f;
#pragma unroll
    for (int ks = 0; ks < 4; ++ks) {
      bf16x8 kf[2];
#pragma unroll
      for (int mt = 0; mt < 2; ++mt) {
        int m = mt * 32 + L;
        int cc = (2 * ks + h2) ^ (m & 7);
        kf[mt] = *(const bf16x8*)(sm + m * 128 + cc * 16);
      }
#pragma unroll
      for (int mt = 0; mt < 2; ++mt)
#pragma unroll
        for (int nt = 0; nt < 2; ++nt)
          accS[mt][nt] = __builtin_amdgcn_mfma_f32_32x32x16_bf16(kf[mt], qf[nt][ks], accS[mt][nt], 0, 0, 0);
    }

#pragma unroll
    for (int nt = 0; nt < 2; ++nt) {
      float mx = -__builtin_inff();
#pragma unroll
      for (int mt = 0; mt < 2; ++mt)
#pragma unroll
        for (int r = 0; r < 16; ++r) mx = fmaxf(mx, accS[mt][nt][r]);
      mx = fmaxf(mx, __shfl_xor(mx, 32));
      float mnew = fmaxf(m_run[nt], mx);
      float alpha = exp2f((m_run[nt] - mnew) * C2);
      m_run[nt] = mnew;
      float mb = mnew * C2;
      float ss = 0.f;
#pragma unroll
      for (int mt = 0; mt < 2; ++mt)
#pragma unroll
        for (int r = 0; r < 16; ++r) {
          float p = exp2f(accS[mt][nt][r] * C2 - mb);
          accS[mt][nt][r] = p;
          ss += p;
        }
      ss += __shfl_xor(ss, 32);
      l_run[nt] = l_run[nt] * alpha + ss;
#pragma unroll
      for (int vt = 0; vt < 2; ++vt)
#pragma unroll
        for (int r = 0; r < 16; ++r) accO[vt][nt][r] *= alpha;
#pragma unroll
      for (int mt = 0; mt < 2; ++mt)
#pragma unroll
        for (int g = 0; g < 4; ++g) {
          unsigned a0 = pk2(accS[mt][nt][4 * g], accS[mt][nt][4 * g + 1]);
          unsigned a1 = pk2(accS[mt][nt][4 * g + 2], accS[mt][nt][4 * g + 3]);
          *(uint2*)(Pb + (nt * 32 + L) * 144 + (mt * 32 + 8 * g + 4 * h2) * 2) = make_uint2(a0, a1);
        }
    }

#pragma unroll
    for (int ks = 0; ks < 4; ++ks) {
      bf16x8 pf[2], vf[2];
#pragma unroll
      for (int nt = 0; nt < 2; ++nt)
        pf[nt] = *(const bf16x8*)(Pb + (nt * 32 + L) * 144 + ks * 32 + h2 * 16);
#pragma unroll
      for (int vt = 0; vt < 2; ++vt) {
        int v = vt * 32 + L;
        int cc = (2 * ks + h2) ^ (v & 7);
        vf[vt] = *(const bf16x8*)(sm + 8192 + v * 128 + cc * 16);
      }
#pragma unroll
      for (int vt = 0; vt < 2; ++vt)
#pragma unroll
        for (int nt = 0; nt < 2; ++nt)
          accO[vt][nt] = __builtin_amdgcn_mfma_f32_32x32x16_bf16(vf[vt], pf[nt], accO[vt][nt], 0, 0, 0);
    }
    __syncthreads();
  }

  const size_t ob = ((size_t)(sp * 16 + h)) * 64 * 4096;
#pragma unroll
  for (int vt = 0; vt < 2; ++vt)
#pragma unroll
    for (int nt = 0; nt < 2; ++nt)
#pragma unroll
      for (int r = 0; r < 16; ++r) {
        int v = vt * 32 + (r & 3) + 8 * (r >> 2) + 4 * h2;
        Op[ob + (size_t)v * 4096 + n0 + nt * 32 + L] = accO[vt][nt][r];
      }
  if (h2 == 0) {
#pragma unroll
    for (int nt = 0; nt < 2; ++nt) {
      int idx = (sp * 16 + h) * 4096 + n0 + nt * 32 + L;
      Mst[idx] = m_run[nt];
      Lst[idx] = l_run[nt];
    }
  }
}

// ---------------- combine splits + transpose to out[n][h*64+v] ----------------
__global__ __launch_bounds__(256) void comb_k(
    const float* __restrict__ Op, const float* __restrict__ Mst, const float* __restrict__ Lst,
    float* __restrict__ out) {
  int h = blockIdx.x & 15, nb = blockIdx.x >> 4;
  __shared__ float w1s[64], w2s[64];
  __shared__ __align__(16) float tile[64 * 68];
  int t = threadIdx.x;
  if (t < 64) {
    int n = nb * 64 + t;
    float m1 = Mst[h * 4096 + n], m2 = Mst[(16 + h) * 4096 + n];
    float l1 = Lst[h * 4096 + n], l2 = Lst[(16 + h) * 4096 + n];
    float M = fmaxf(m1, m2);
    float aw = exp2f((m1 - M) * C2), bw = exp2f((m2 - M) * C2);
    float inv = 1.f / (l1 * aw + l2 * bw);
    w1s[t] = aw * inv;
    w2s[t] = bw * inv;
  }
  __syncthreads();
  {
    int v = t >> 2, nc = t & 3;
    size_t base1 = ((size_t)(h * 64 + v)) * 4096 + nb * 64 + nc * 16;
    size_t base2 = ((size_t)((16 + h) * 64 + v)) * 4096 + nb * 64 + nc * 16;
#pragma unroll
    for (int c = 0; c < 4; ++c) {
      float4 x1 = *(const float4*)(Op + base1 + 4 * c);
      float4 x2 = *(const float4*)(Op + base2 + 4 * c);
      int nl = nc * 16 + 4 * c;
      tile[(nl + 0) * 68 + v] = x1.x * w1s[nl + 0] + x2.x * w2s[nl + 0];
      tile[(nl + 1) * 68 + v] = x1.y * w1s[nl + 1] + x2.y * w2s[nl + 1];
      tile[(nl + 2) * 68 + v] = x1.z * w1s[nl + 2] + x2.z * w2s[nl + 2];
      tile[(nl + 3) * 68 + v] = x1.w * w1s[nl + 3] + x2.w * w2s[nl + 3];
    }
  }
  __syncthreads();
  {
    int n = t >> 2, c0 = t & 3;
#pragma unroll
    for (int i = 0; i < 4; ++i) {
      int ch = c0 + 4 * i;
      float4 vv = *(const float4*)&tile[n * 68 + ch * 4];
      *(float4*)(out + ((size_t)(nb * 64 + n)) * 1024 + h * 64 + ch * 4) = vv;
    }
  }
}

extern "C" void kernel_launch(void* const* d_in, const int* in_sizes, int n_in,
                              void* d_out, int out_size, void* d_ws, size_t ws_size,
                              hipStream_t stream) {
  const float* XQ = (const float*)d_in[0];
  const float* XK = (const float*)d_in[1];
  const float* XV = (const float*)d_in[2];
  const float* Wq = (const float*)d_in[3];
  const float* bq = (const float*)d_in[4];
  const float* Wk = (const float*)d_in[5];
  const float* bk = (const float*)d_in[6];
  const float* Wv = (const float*)d_in[7];
  const float* bv = (const float*)d_in[8];

  const size_t MB = 1024 * 1024;
  char* w = (char*)d_ws;
  u16* xqb = (u16*)(w + 0 * MB);
  u16* xkb = (u16*)(w + 8 * MB);
  u16* xvb = (u16*)(w + 16 * MB);
  u16* wtq = (u16*)(w + 24 * MB);
  u16* wtk = (u16*)(w + 26 * MB);
  u16* wtv = (u16*)(w + 28 * MB);
  u16* Qb = (u16*)(w + 32 * MB);
  u16* Kb = (u16*)(w + 40 * MB);
  u16* Vb = (u16*)(w + 48 * MB);
  u16* VTb = (u16*)(w + 56 * MB);
  float* Op = (float*)(w + 0);            // 32 MB, reuses conversion region (dead by then)
  float* Mst = (float*)(w + 64 * MB);     // 512 KB
  float* Lst = (float*)(w + 64 * MB + 524288);

  convx_k<<<dim3(2048, 1, 3), 256, 0, stream>>>(XQ, XK, XV, xqb, xkb, xvb);
  convw_k<<<dim3(256, 1, 3), 256, 0, stream>>>(Wq, Wk, Wv, wtq, wtk, wtv);
  proj_k<<<dim3(8, 32, 3), 256, 0, stream>>>(xqb, xkb, xvb, wtq, wtk, wtv,
                                             bq, bk, bv, Qb, Kb, Vb);
  vtrans_k<<<dim3(1024), 256, 0, stream>>>(Vb, VTb);
  attn_k<<<dim3(1024), 128, 0, stream>>>(Qb, Kb, VTb, Op, Mst, Lst);
  comb_k<<<dim3(1024), 256, 0, stream>>>(Op, Mst, Lst, (float*)d_out);
}

// Round 2
// 268.035 us; speedup vs baseline: 1.2599x; 1.2599x over previous
//
#include <hip/hip_runtime.h>

typedef unsigned short u16;
typedef __attribute__((ext_vector_type(8))) short bf16x8;
typedef __attribute__((ext_vector_type(16))) float floatx16;

#define C2 0.18033688011112042f  // log2(e)/8 : folds the 1/sqrt(64) score scale into exp2

static __device__ __forceinline__ u16 f2b(float f) {
  unsigned u = __builtin_bit_cast(unsigned, f);
  u = (u + 0x7FFFu + ((u >> 16) & 1u)) >> 16;  // RNE fp32->bf16
  return (u16)u;
}
static __device__ __forceinline__ unsigned pk2(float a, float b) {
  return (unsigned)f2b(a) | ((unsigned)f2b(b) << 16);
}
static __device__ __forceinline__ void gl_lds16(const void* g, void* l) {
  __builtin_amdgcn_global_load_lds(
      (const __attribute__((address_space(1))) unsigned*)g,
      (__attribute__((address_space(3))) unsigned*)l, 16, 0, 0);
}
static __device__ __forceinline__ float ex2(float x) {
#if __has_builtin(__builtin_amdgcn_exp2f)
  return __builtin_amdgcn_exp2f(x);
#else
  return exp2f(x);
#endif
}
// pack trunc(a)|trunc(b)<<16 in ONE v_perm_b32 (bytes a.2,a.3,b.2,b.3)
static __device__ __forceinline__ unsigned pkt(float a, float b) {
#if __has_builtin(__builtin_amdgcn_perm)
  return __builtin_amdgcn_perm(__builtin_bit_cast(unsigned, a),
                               __builtin_bit_cast(unsigned, b), 0x03020706u);
#else
  return (__builtin_bit_cast(unsigned, a) >> 16) |
         (__builtin_bit_cast(unsigned, b) & 0xffff0000u);
#endif
}
// 32-lane row swap: a <- {a.lo, b.lo}, b <- {a.hi, b.hi}  (MFMA C->B layout transform)
static __device__ __forceinline__ void pswap(unsigned& a, unsigned& b) {
#if __has_builtin(__builtin_amdgcn_permlane32_swap)
  auto r = __builtin_amdgcn_permlane32_swap(a, b, false, false);
  a = r[0];
  b = r[1];
#else
  unsigned ta = (unsigned)__shfl_xor((int)a, 32);
  unsigned tb = (unsigned)__shfl_xor((int)b, 32);
  bool hi = (threadIdx.x & 32) != 0;
  unsigned na = hi ? tb : a;
  unsigned nb = hi ? b : ta;
  a = na;
  b = nb;
#endif
}

// ---------------- convert X: f32 -> bf16, flat ----------------
__global__ __launch_bounds__(256) void convx_k(
    const float* __restrict__ x0, const float* __restrict__ x1, const float* __restrict__ x2,
    u16* __restrict__ o0, u16* __restrict__ o1, u16* __restrict__ o2) {
  int z = blockIdx.z;
  const float* x = z == 0 ? x0 : (z == 1 ? x1 : x2);
  u16* o = z == 0 ? o0 : (z == 1 ? o1 : o2);
  size_t i = ((size_t)blockIdx.x * 256 + threadIdx.x) * 8;
  float4 a = *(const float4*)(x + i);
  float4 b = *(const float4*)(x + i + 4);
  uint4 u;
  u.x = pk2(a.x, a.y); u.y = pk2(a.z, a.w);
  u.z = pk2(b.x, b.y); u.w = pk2(b.z, b.w);
  *(uint4*)(o + i) = u;
}

// ------- convert+transpose W: [H][1024][64] f32 -> Wt[(h*64+col)][1024] bf16 -------
__global__ __launch_bounds__(256) void convw_k(
    const float* __restrict__ w0, const float* __restrict__ w1, const float* __restrict__ w2,
    u16* __restrict__ o0, u16* __restrict__ o1, u16* __restrict__ o2) {
  int z = blockIdx.z;
  const float* W = z == 0 ? w0 : (z == 1 ? w1 : w2);
  u16* O = z == 0 ? o0 : (z == 1 ? o1 : o2);
  int h = blockIdx.x >> 4, d0 = (blockIdx.x & 15) * 64;
  __shared__ __align__(16) float tile[64 * 68];
  int t = threadIdx.x;
  {
    int r = t >> 2, c = t & 3;
    const float* src = W + (size_t)h * 65536 + (size_t)(d0 + r) * 64 + c * 16;
#pragma unroll
    for (int i = 0; i < 4; ++i) {
      float4 v = *(const float4*)(src + 4 * i);
      *(float4*)&tile[r * 68 + c * 16 + 4 * i] = v;
    }
  }
  __syncthreads();
  {
    int k = t >> 2, dc = t & 3;
    unsigned u[8];
#pragma unroll
    for (int i = 0; i < 8; ++i) {
      float a = tile[(dc * 16 + 2 * i) * 68 + k];
      float b = tile[(dc * 16 + 2 * i + 1) * 68 + k];
      u[i] = pk2(a, b);
    }
    u16* dst = O + ((size_t)(h * 64 + k)) * 1024 + d0 + dc * 16;
    *(uint4*)dst = make_uint4(u[0], u[1], u[2], u[3]);
    *(uint4*)(dst + 8) = make_uint4(u[4], u[5], u[6], u[7]);
  }
}

// ---------------- projection GEMM: C[n][col] = X[n][:] . Wt[col][:] + b[col] ----------------
__global__ __launch_bounds__(256, 3) void proj_k(
    const u16* __restrict__ x0, const u16* __restrict__ x1, const u16* __restrict__ x2,
    const u16* __restrict__ w0, const u16* __restrict__ w1, const u16* __restrict__ w2,
    const float* __restrict__ b0, const float* __restrict__ b1, const float* __restrict__ b2,
    u16* __restrict__ q0, u16* __restrict__ q1, u16* __restrict__ q2) {
  int z = blockIdx.z;
  const u16* X = z == 0 ? x0 : (z == 1 ? x1 : x2);
  const u16* Wt = z == 0 ? w0 : (z == 1 ? w1 : w2);
  const float* bias = z == 0 ? b0 : (z == 1 ? b1 : b2);
  u16* out = z == 0 ? q0 : (z == 1 ? q1 : q2);

  __shared__ uint4 smem4[16384 / 16];
  char* sm = (char*)smem4;
  const int t = threadIdx.x, lane = t & 63, wid = t >> 6;
  const int L = lane & 31, h2 = lane >> 5;
  const int wm = wid >> 1, wc = wid & 1;
  const int n0 = blockIdx.y * 128, c0 = blockIdx.x * 128;

  floatx16 acc[2][2];
#pragma unroll
  for (int a = 0; a < 2; ++a)
#pragma unroll
    for (int b = 0; b < 2; ++b)
#pragma unroll
      for (int r = 0; r < 16; ++r) acc[a][b][r] = 0.f;

  const int srow = t >> 2, sc = t & 3;
  for (int k0 = 0; k0 < 1024; k0 += 32) {
#pragma unroll
    for (int i = 0; i < 2; ++i) {
      int row = i * 64 + srow;
      int cg = sc ^ ((row >> 1) & 3);
      gl_lds16(X + (size_t)(n0 + row) * 1024 + k0 + cg * 8, sm + i * 4096 + wid * 1024);
    }
#pragma unroll
    for (int i = 0; i < 2; ++i) {
      int row = i * 64 + srow;
      int cg = sc ^ ((row >> 1) & 3);
      gl_lds16(Wt + (size_t)(c0 + row) * 1024 + k0 + cg * 8, sm + 8192 + i * 4096 + wid * 1024);
    }
    __syncthreads();
#pragma unroll
    for (int ks = 0; ks < 2; ++ks) {
      bf16x8 af[2], bfr[2];
#pragma unroll
      for (int mt = 0; mt < 2; ++mt) {
        int m = wm * 64 + mt * 32 + L;
        int cc = (2 * ks + h2) ^ ((m >> 1) & 3);
        af[mt] = *(const bf16x8*)(sm + m * 64 + cc * 16);
      }
#pragma unroll
      for (int ct = 0; ct < 2; ++ct) {
        int c = wc * 64 + ct * 32 + L;
        int cc = (2 * ks + h2) ^ ((c >> 1) & 3);
        bfr[ct] = *(const bf16x8*)(sm + 8192 + c * 64 + cc * 16);
      }
#pragma unroll
      for (int mt = 0; mt < 2; ++mt)
#pragma unroll
        for (int ct = 0; ct < 2; ++ct)
          acc[mt][ct] = __builtin_amdgcn_mfma_f32_32x32x16_bf16(af[mt], bfr[ct], acc[mt][ct], 0, 0, 0);
    }
    __syncthreads();
  }
#pragma unroll
  for (int ct = 0; ct < 2; ++ct) {
    int gcol = c0 + wc * 64 + ct * 32 + L;
    float bv = bias[gcol];
    int h = gcol >> 6, cl = gcol & 63;
#pragma unroll
    for (int mt = 0; mt < 2; ++mt)
#pragma unroll
      for (int r = 0; r < 16; ++r) {
        int seq = n0 + wm * 64 + mt * 32 + (r & 3) + 8 * (r >> 2) + 4 * h2;
        out[((size_t)h * 4096 + seq) * 64 + cl] = f2b(acc[mt][ct][r] + bv);
      }
  }
}

// ---------------- V transpose: V[h][n][v] -> VT[h][v][n] (bf16) ----------------
__global__ __launch_bounds__(256) void vtrans_k(const u16* __restrict__ V, u16* __restrict__ VT) {
  int h = blockIdx.x & 15, nb = blockIdx.x >> 4;
  __shared__ __align__(16) u16 tile[64 * 72];
  int t = threadIdx.x;
  {
    int r = t >> 2, c = t & 3;
    const u16* src = V + ((size_t)(h * 4096 + nb * 64 + r)) * 64 + c * 16;
    *(bf16x8*)&tile[r * 72 + c * 16] = *(const bf16x8*)src;
    *(bf16x8*)&tile[r * 72 + c * 16 + 8] = *(const bf16x8*)(src + 8);
  }
  __syncthreads();
  {
    int v = t >> 2, nc = t & 3;
    unsigned u[8];
#pragma unroll
    for (int i = 0; i < 8; ++i) {
      unsigned lo = tile[(nc * 16 + 2 * i) * 72 + v];
      unsigned hi = tile[(nc * 16 + 2 * i + 1) * 72 + v];
      u[i] = lo | (hi << 16);
    }
    u16* dst = VT + ((size_t)(h * 64 + v)) * 4096 + nb * 64 + nc * 16;
    *(uint4*)dst = make_uint4(u[0], u[1], u[2], u[3]);
    *(uint4*)(dst + 8) = make_uint4(u[4], u[5], u[6], u[7]);
  }
}

// ---------------- flash attention, barrier-free K-loop ----------------
// Block = 4 waves = 64 queries; waves split the 4096 keys into interleaved 32-key
// stripes (32 rounds x 128 keys/block). Per wave-round: K frags direct from global
// (L1-resident), V^T stripe in wave-private double-buffered LDS via global_load_lds;
// S^T = K.Q^T; softmax per column (lane); P^T -> PV B-frags via v_permlane32_swap
// (no LDS round-trip); O^T += V^T.P^T. End: 4-way m/l/O combine in LDS, direct out.
__global__ __launch_bounds__(256, 3) void attn_k(
    const u16* __restrict__ Q, const u16* __restrict__ K, const u16* __restrict__ VT,
    float* __restrict__ out) {
  __shared__ uint4 smem4[34816 / 16];
  char* sm = (char*)smem4;  // [0,32K): VT dbuf 4 waves x 2 x 4KB ; [32K,34K): stats
  const int t = threadIdx.x, lane = t & 63, w = t >> 6;
  const int L = lane & 31, h2 = lane >> 5;
  const int h = blockIdx.x & 15, qt = blockIdx.x >> 4;  // h in low bits -> XCD L2 locality
  const int n0 = qt * 64;
  const u16* Qg = Q + (size_t)h * 4096 * 64;
  const u16* Kg = K + (size_t)h * 4096 * 64;
  const u16* VTg = VT + (size_t)h * 64 * 4096;
  char* buf0 = sm + w * 8192;
  char* buf1 = buf0 + 4096;

  // persistent Q fragments (B-operand: col = n = nt*32+L, k = ks*16+8*h2+j)
  bf16x8 qf[2][4];
#pragma unroll
  for (int nt = 0; nt < 2; ++nt)
#pragma unroll
    for (int ks = 0; ks < 4; ++ks)
      qf[nt][ks] = *(const bf16x8*)(Qg + ((size_t)(n0 + nt * 32 + L)) * 64 + ks * 16 + h2 * 8);

  floatx16 accO[2][2];
#pragma unroll
  for (int a = 0; a < 2; ++a)
#pragma unroll
    for (int b = 0; b < 2; ++b)
#pragma unroll
      for (int r = 0; r < 16; ++r) accO[a][b][r] = 0.f;
  float m_run[2] = {-1e30f, -1e30f};
  float l_run[2] = {0.f, 0.f};

  // stage VT stripe [64 v][32 m] for round rn into wave-private buf (4KB, 4 issues)
  auto stage = [&](int rn, char* buf) {
    int m0n = rn * 128 + w * 32;
#pragma unroll
    for (int i = 0; i < 4; ++i) {
      int c = i * 64 + lane;
      int v = c >> 2, mc = c & 3;
      gl_lds16(VTg + (size_t)v * 4096 + m0n + ((mc ^ (v & 3)) << 3), buf + i * 1024);
    }
  };
  stage(0, buf0);

  for (int r = 0; r < 32; ++r) {
    char* bufc = (r & 1) ? buf1 : buf0;
    char* bufn = (r & 1) ? buf0 : buf1;
    const int m0 = r * 128 + w * 32;

    // K frags direct from global (A-operand rows m = m0+L), BEFORE next-round stage:
    // the vmcnt wait for kf then also proves this round's gl_lds retired.
    bf16x8 kf[4];
    {
      const u16* Kw = Kg + ((size_t)(m0 + L)) * 64 + h2 * 8;
#pragma unroll
      for (int ks = 0; ks < 4; ++ks) kf[ks] = *(const bf16x8*)(Kw + ks * 16);
    }
    if (r != 31) stage(r + 1, bufn);

    floatx16 accS[2];
#pragma unroll
    for (int nt = 0; nt < 2; ++nt)
#pragma unroll
      for (int q = 0; q < 16; ++q) accS[nt][q] = 0.f;
#pragma unroll
    for (int ks = 0; ks < 4; ++ks) {
      accS[0] = __builtin_amdgcn_mfma_f32_32x32x16_bf16(kf[ks], qf[0][ks], accS[0], 0, 0, 0);
      accS[1] = __builtin_amdgcn_mfma_f32_32x32x16_bf16(kf[ks], qf[1][ks], accS[1], 0, 0, 0);
    }

    unsigned pkr[2][8];
#pragma unroll
    for (int nt = 0; nt < 2; ++nt) {
      float mx = accS[nt][0];
#pragma unroll
      for (int q = 1; q < 16; ++q) mx = fmaxf(mx, accS[nt][q]);
      mx = fmaxf(mx, __shfl_xor(mx, 32));
      if (!__all(mx <= m_run[nt])) {  // running max changed somewhere: rescale
        float mnew = fmaxf(m_run[nt], mx);
        float al = ex2((m_run[nt] - mnew) * C2);
        m_run[nt] = mnew;
        l_run[nt] *= al;
#pragma unroll
        for (int vt = 0; vt < 2; ++vt)
#pragma unroll
          for (int q = 0; q < 16; ++q) accO[vt][nt][q] *= al;
      }
      float mb = m_run[nt] * C2;
      float ss = 0.f;
      float p[16];
#pragma unroll
      for (int q = 0; q < 16; ++q) {
        p[q] = ex2(fmaf(accS[nt][q], C2, -mb));
        // sum the TRUNCATED value so l matches stored bf16 P exactly (no bias)
        ss += __builtin_bit_cast(float, __builtin_bit_cast(unsigned, p[q]) & 0xffff0000u);
      }
      ss += __shfl_xor(ss, 32);
      l_run[nt] += ss;
#pragma unroll
      for (int g = 0; g < 8; ++g) pkr[nt][g] = pkt(p[2 * g], p[2 * g + 1]);
      // C-layout -> B-operand layout: 4 row-swaps produce frags for both 16-chunks
      pswap(pkr[nt][0], pkr[nt][2]);
      pswap(pkr[nt][1], pkr[nt][3]);
      pswap(pkr[nt][4], pkr[nt][6]);
      pswap(pkr[nt][5], pkr[nt][7]);
    }

#pragma unroll
    for (int c2 = 0; c2 < 2; ++c2) {
      bf16x8 pf[2];
#pragma unroll
      for (int nt = 0; nt < 2; ++nt) {
        uint4 u = make_uint4(pkr[nt][c2 * 4], pkr[nt][c2 * 4 + 1],
                             pkr[nt][c2 * 4 + 2], pkr[nt][c2 * 4 + 3]);
        pf[nt] = __builtin_bit_cast(bf16x8, u);
      }
#pragma unroll
      for (int vt = 0; vt < 2; ++vt) {
        int v = vt * 32 + L;
        int cc = (c2 * 2 + h2) ^ (v & 3);
        bf16x8 vf = *(const bf16x8*)(bufc + v * 64 + cc * 16);
        accO[vt][0] = __builtin_amdgcn_mfma_f32_32x32x16_bf16(vf, pf[0], accO[vt][0], 0, 0, 0);
        accO[vt][1] = __builtin_amdgcn_mfma_f32_32x32x16_bf16(vf, pf[1], accO[vt][1], 0, 0, 0);
      }
    }
  }

  // ---- cross-wave combine (4 key-stripes of the same 64 queries) ----
  float* mstat = (float*)(sm + 32768);  // [4][64]
  float* lstat = mstat + 256;           // [4][64]
  if (h2 == 0) {
    mstat[w * 64 + L] = m_run[0];
    mstat[w * 64 + 32 + L] = m_run[1];
    lstat[w * 64 + L] = l_run[0];
    lstat[w * 64 + 32 + L] = l_run[1];
  }
  __syncthreads();
  float scale[2];
#pragma unroll
  for (int nt = 0; nt < 2; ++nt) {
    int idx = nt * 32 + L;
    float M = mstat[idx];
    M = fmaxf(M, mstat[64 + idx]);
    M = fmaxf(M, mstat[128 + idx]);
    M = fmaxf(M, mstat[192 + idx]);
    float denom = 0.f;
#pragma unroll
    for (int w4 = 0; w4 < 4; ++w4)
      denom += lstat[w4 * 64 + idx] * ex2((mstat[w4 * 64 + idx] - M) * C2);
    scale[nt] = ex2((m_run[nt] - M) * C2) / denom;
  }
  float* Ob = (float*)sm;  // [64 q][68 v] fp32, reuses dead VT bufs
#pragma unroll
  for (int ww = 0; ww < 4; ++ww) {
    if (w == ww) {
#pragma unroll
      for (int vt = 0; vt < 2; ++vt)
#pragma unroll
        for (int nt = 0; nt < 2; ++nt)
#pragma unroll
          for (int q = 0; q < 16; ++q) {
            int idx = (nt * 32 + L) * 68 + vt * 32 + (q & 3) + 8 * (q >> 2) + 4 * h2;
            float val = accO[vt][nt][q] * scale[nt];
            if (ww == 0) Ob[idx] = val;
            else Ob[idx] += val;
          }
    }
    __syncthreads();
  }
  {
    int q = t >> 2, c = t & 3;
    float* dst = out + ((size_t)(n0 + q)) * 1024 + h * 64 + c * 16;
    const float* src = &Ob[q * 68 + c * 16];
#pragma unroll
    for (int i = 0; i < 4; ++i) *(float4*)(dst + 4 * i) = *(const float4*)(src + 4 * i);
  }
}

extern "C" void kernel_launch(void* const* d_in, const int* in_sizes, int n_in,
                              void* d_out, int out_size, void* d_ws, size_t ws_size,
                              hipStream_t stream) {
  const float* XQ = (const float*)d_in[0];
  const float* XK = (const float*)d_in[1];
  const float* XV = (const float*)d_in[2];
  const float* Wq = (const float*)d_in[3];
  const float* bq = (const float*)d_in[4];
  const float* Wk = (const float*)d_in[5];
  const float* bk = (const float*)d_in[6];
  const float* Wv = (const float*)d_in[7];
  const float* bv = (const float*)d_in[8];

  const size_t MB = 1024 * 1024;
  char* w = (char*)d_ws;
  u16* xqb = (u16*)(w + 0 * MB);
  u16* xkb = (u16*)(w + 8 * MB);
  u16* xvb = (u16*)(w + 16 * MB);
  u16* wtq = (u16*)(w + 24 * MB);
  u16* wtk = (u16*)(w + 26 * MB);
  u16* wtv = (u16*)(w + 28 * MB);
  u16* Qb = (u16*)(w + 32 * MB);
  u16* Kb = (u16*)(w + 40 * MB);
  u16* Vb = (u16*)(w + 48 * MB);
  u16* VTb = (u16*)(w + 56 * MB);

  convx_k<<<dim3(2048, 1, 3), 256, 0, stream>>>(XQ, XK, XV, xqb, xkb, xvb);
  convw_k<<<dim3(256, 1, 3), 256, 0, stream>>>(Wq, Wk, Wv, wtq, wtk, wtv);
  proj_k<<<dim3(8, 32, 3), 256, 0, stream>>>(xqb, xkb, xvb, wtq, wtk, wtv,
                                             bq, bk, bv, Qb, Kb, Vb);
  vtrans_k<<<dim3(1024), 256, 0, stream>>>(Vb, VTb);
  attn_k<<<dim3(1024), 256, 0, stream>>>(Qb, Kb, VTb, (float*)d_out);
}